// Round 3
// baseline (874.879 us; speedup 1.0000x reference)
//
#include <hip/hip_runtime.h>

// 2-layer LSTM, B=512, T=1024, H=64 (tf LSTMCell, gates i,j,f,o, forget bias 1.0)
// One block (320 thr = 5 waves) per batch element, grid 512 (2 blocks/CU).
//
// ROUND-3 RESTRUCTURE: rounds 1-2 were paced by the LDS instruction pipe
// (~128 broadcast ds_read_b128 per CU per step ~= 1536 cyc ~= measured step
// time; all-lanes-same-address reads deliver 16 useful bytes per inst).
// This version removes ALL LDS traffic from the h1 matvec:
//   Waves 0-3: wave g owns gate g (columns 64g..64g+63); lane u owns column
//   g*64+u with all 65 W1 weights in VGPRs (no split-k). The h1 vector lives
//   REPLICATED IN REGISTERS (h1[u] in lane u of every wave, produced by the
//   replicated cell update); the matvec broadcasts h1[j] via v_readlane ->
//   SGPR -> FMA. Zero LDS reads in the matvec.
//   Cross-wave exchange per step: one stride-1 gs write + barrier + 4 scalar
//   gs reads (gate vectors), i.e. ~6 LDS insts/step/block vs ~100 before.
//   Wave 0 additionally publishes h1 to LDS for the layer-2 wave.
//   Wave 4: full layer-2 recurrence, one step behind (parity-buffered h1s).
// __launch_bounds__(320,2) keeps the VGPR cap at 256 so the 65 weights/thread
// stay register-resident (earlier remat failure came from a 64-VGPR target).

#define TT 1024

__device__ __forceinline__ float fsig(float x) {
    return __builtin_amdgcn_rcpf(1.f + __expf(-x));
}
__device__ __forceinline__ float ftanh(float x) {
    return 1.f - 2.f * __builtin_amdgcn_rcpf(1.f + __expf(2.f * x));
}

template <int Ctrl, int Rmask>
__device__ __forceinline__ float dpp_add(float x) {
    int t = __builtin_amdgcn_update_dpp(0, __float_as_int(x), Ctrl, Rmask, 0xf, true);
    return x + __int_as_float(t);
}
// Sum across 64 lanes; result valid in lane 63. 6 dependent VALU ops.
__device__ __forceinline__ float wave_sum64(float x) {
    x = dpp_add<0x111, 0xf>(x); // row_shr:1
    x = dpp_add<0x112, 0xf>(x); // row_shr:2
    x = dpp_add<0x114, 0xf>(x); // row_shr:4
    x = dpp_add<0x118, 0xf>(x); // row_shr:8
    x = dpp_add<0x142, 0xa>(x); // row_bcast:15
    x = dpp_add<0x143, 0xc>(x); // row_bcast:31 ; lane63 = total
    return x;
}

// Broadcast lane `l` of v to all lanes via SGPR (no LDS, exec-independent).
__device__ __forceinline__ float bcast(float v, int l) {
#if __has_builtin(__builtin_amdgcn_readlane)
    return __uint_as_float(__builtin_amdgcn_readlane(__float_as_uint(v), l));
#else
    return __shfl(v, l);
#endif
}

__global__ __launch_bounds__(320, 2) void lstm2_kernel(
    const float* __restrict__ x,    // [B, T]
    const float* __restrict__ W1,   // [65, 256]; row0 = x, rows 1..64 = h1
    const float* __restrict__ b1,   // [256]
    const float* __restrict__ W2,   // [65, 4]; rows 0..63 = h1, row 64 = h2
    const float* __restrict__ b2,   // [4]
    float* __restrict__ y)          // [B, T]
{
    __shared__ __align__(16) float xs[TT];
    __shared__ __align__(16) float h1s[2][64];    // parity-buffered h1 (for wave 4)
    __shared__ __align__(16) float gs[2][4][64];  // parity-buffered gates [gate][unit]

    const int tid  = threadIdx.x;
    const int b    = blockIdx.x;
    const int lane = tid & 63;
    const int cw   = tid >> 6;        // 0..3 compute (gate = cw), 4 = layer-2

    // stage x row into LDS (coalesced float4)
    if (tid < 256) {
        ((float4*)xs)[tid] = ((const float4*)(x + (size_t)b * TT))[tid];
    }

    float* yrow = y + (size_t)b * TT;

    if (cw < 4) {
        // ---------------- compute waves ----------------
        const int col = (cw << 6) | lane;     // gate column: gate*64 + unit

        // full column of W1 in registers: 65 weights + bias
        float w[65];
        const float bias = b1[col];
        w[0] = W1[col];                       // x-row weight
#pragma unroll
        for (int j = 1; j <= 64; ++j) w[j] = W1[j * 256 + col];   // h1 rows

        // unified activation constants (wave-uniform, branch-free):
        //   act = aa + bb * rcp(1 + exp2(mm*p + kk))
        //   i,o: sigmoid(p); f: sigmoid(p+1); j: tanh(p)
        const float L2E = 1.4426950408889634f;
        const float mm = (cw == 1) ? 2.f * L2E : -L2E;
        const float kk = (cw == 2) ? -L2E : 0.f;
        const float aa = (cw == 1) ? 1.f : 0.f;
        const float bb = (cw == 1) ? -2.f : 1.f;

        float c1 = 0.f;   // cell state of unit `lane` (replicated per wave)
        float hv = 0.f;   // h1[lane] (replicated per wave, REGISTER-resident)
        __syncthreads();  // barrier #1 (xs staged)

        // One step; PAR compile-time. Matvec broadcasts hv lane-by-lane via
        // readlane (pure VALU). Only cross-wave traffic: gs write/read.
#define STEP(PAR, XT) { \
        float a0 = fmaf((XT), w[0], bias), a1 = 0.f, a2 = 0.f, a3 = 0.f; \
        _Pragma("unroll") \
        for (int j = 0; j < 64; j += 4) { \
            a0 = fmaf(bcast(hv, j + 0), w[j + 1], a0); \
            a1 = fmaf(bcast(hv, j + 1), w[j + 2], a1); \
            a2 = fmaf(bcast(hv, j + 2), w[j + 3], a2); \
            a3 = fmaf(bcast(hv, j + 3), w[j + 4], a3); \
        } \
        float p = (a0 + a1) + (a2 + a3); \
        float act = fmaf(bb, __builtin_amdgcn_rcpf(1.f + exp2f(fmaf(mm, p, kk))), aa); \
        gs[PAR][cw][lane] = act; \
        __syncthreads(); \
        { \
            float i_ = gs[PAR][0][lane], j_ = gs[PAR][1][lane]; \
            float f_ = gs[PAR][2][lane], o_ = gs[PAR][3][lane]; \
            c1 = fmaf(c1, f_, i_ * j_); \
            float rr = __builtin_amdgcn_rcpf(1.f + exp2f(c1 * (2.f * 1.4426950408889634f))); \
            hv = fmaf(-2.f, rr * o_, o_); \
            if (cw == 0) h1s[PAR][lane] = hv; \
        } }

        for (int t = 0; t < TT; t += 4) {
            float4 x4 = *(const float4*)(xs + t);
            STEP(0, x4.x)
            STEP(1, x4.y)
            STEP(0, x4.z)
            STEP(1, x4.w)
        }
#undef STEP
        __syncthreads();              // tail barrier (publish h1(TT-1))
    } else {
        // ---------------- wave 4: full layer 2, one step behind ----------------
        float4 w2g4 = *(const float4*)(W2 + lane * 4);   // W2[lane][0..3]
        const float w2h0 = W2[256], w2h1 = W2[257], w2h2 = W2[258], w2h3 = W2[259];
        const float b20 = b2[0], b21 = b2[1], b22 = b2[2], b23 = b2[3];
        float c2 = 0.f, h2 = 0.f;     // state lives in lane 63
        __syncthreads();              // barrier #1

        for (int t = 0; t < TT; ++t) {
            __syncthreads();          // rendezvous with compute mid-step barrier
            if (t > 0) {
                const float hv = h1s[(t - 1) & 1][lane];   // h1(t-1)
                const float d0 = wave_sum64(hv * w2g4.x);
                const float d1 = wave_sum64(hv * w2g4.y);
                const float d2 = wave_sum64(hv * w2g4.z);
                const float d3 = wave_sum64(hv * w2g4.w);
                if (lane == 63) {
                    const float i2 = fsig (fmaf(h2, w2h0, d0) + b20);
                    const float j2 = ftanh(fmaf(h2, w2h1, d1) + b21);
                    const float f2 = fsig (fmaf(h2, w2h2, d2) + b22 + 1.f);
                    const float o2 = fsig (fmaf(h2, w2h3, d3) + b23);
                    c2 = fmaf(c2, f2, i2 * j2);
                    h2 = ftanh(c2) * o2;
                    yrow[t - 1] = h2;
                }
            }
        }
        __syncthreads();              // matches compute tail barrier
        {   // final step (t = TT-1)
            const float hv = h1s[(TT - 1) & 1][lane];
            const float d0 = wave_sum64(hv * w2g4.x);
            const float d1 = wave_sum64(hv * w2g4.y);
            const float d2 = wave_sum64(hv * w2g4.z);
            const float d3 = wave_sum64(hv * w2g4.w);
            if (lane == 63) {
                const float i2 = fsig (fmaf(h2, w2h0, d0) + b20);
                const float j2 = ftanh(fmaf(h2, w2h1, d1) + b21);
                const float f2 = fsig (fmaf(h2, w2h2, d2) + b22 + 1.f);
                const float o2 = fsig (fmaf(h2, w2h3, d3) + b23);
                c2 = fmaf(c2, f2, i2 * j2);
                h2 = ftanh(c2) * o2;
                yrow[TT - 1] = h2;
            }
        }
    }
}

extern "C" void kernel_launch(void* const* d_in, const int* in_sizes, int n_in,
                              void* d_out, int out_size, void* d_ws, size_t ws_size,
                              hipStream_t stream) {
    const float* x  = (const float*)d_in[0];
    const float* W1 = (const float*)d_in[1];
    const float* b1 = (const float*)d_in[2];
    const float* W2 = (const float*)d_in[3];
    const float* b2 = (const float*)d_in[4];
    float* y = (float*)d_out;
    lstm2_kernel<<<512, 320, 0, stream>>>(x, W1, b1, W2, b2, y);
}

// Round 4
// 874.453 us; speedup vs baseline: 1.0005x; 1.0005x over previous
//
#include <hip/hip_runtime.h>

// 2-layer LSTM, B=512, T=1024, H=64 (tf LSTMCell, gates i,j,f,o, forget bias 1.0)
// One block (320 thr = 5 waves) per batch element, grid 512 (2 blocks/CU).
//
// Structure (round 3): zero-LDS matvec. Waves 0-3: wave g owns gate g
// (columns 64g..64g+63); lane u owns column g*64+u with all 65 W1 weights in
// VGPRs. h1 lives REPLICATED IN REGISTERS (h1[u] in lane u of every wave);
// the matvec broadcasts h1[j] via v_readlane -> SGPR -> FMA (pure VALU).
// Cross-wave traffic per step: one stride-1 gs write + barrier + 4 scalar gs
// reads. Wave 4: full layer-2 recurrence, one step behind.
//
// ROUND-4 FIX: round 3 regressed (875us, VGPR_Count=44) because the backend
// REMATERIALIZED the 65 weight loads into the t-loop (L1-bound; invisible in
// FETCH_SIZE since W1 is cache-resident). This version pins the weights with
// an empty asm "+v" keep-alive chain at the top of every t-iteration: the
// asm reads AND writes each w[] register, so the next iteration depends on
// the asm output -- a value the compiler cannot rematerialize from memory.
// __launch_bounds__(320,1) gives the allocator the full VGPR budget
// (expect ~110-150 VGPRs; 2 blocks/CU needs <= ~800).

#define TT 1024

__device__ __forceinline__ float fsig(float x) {
    return __builtin_amdgcn_rcpf(1.f + __expf(-x));
}
__device__ __forceinline__ float ftanh(float x) {
    return 1.f - 2.f * __builtin_amdgcn_rcpf(1.f + __expf(2.f * x));
}

template <int Ctrl, int Rmask>
__device__ __forceinline__ float dpp_add(float x) {
    int t = __builtin_amdgcn_update_dpp(0, __float_as_int(x), Ctrl, Rmask, 0xf, true);
    return x + __int_as_float(t);
}
// Sum across 64 lanes; result valid in lane 63. 6 dependent VALU ops.
__device__ __forceinline__ float wave_sum64(float x) {
    x = dpp_add<0x111, 0xf>(x); // row_shr:1
    x = dpp_add<0x112, 0xf>(x); // row_shr:2
    x = dpp_add<0x114, 0xf>(x); // row_shr:4
    x = dpp_add<0x118, 0xf>(x); // row_shr:8
    x = dpp_add<0x142, 0xa>(x); // row_bcast:15
    x = dpp_add<0x143, 0xc>(x); // row_bcast:31 ; lane63 = total
    return x;
}

// Broadcast lane `l` of v to all lanes via SGPR (no LDS, exec-independent).
__device__ __forceinline__ float bcast(float v, int l) {
#if __has_builtin(__builtin_amdgcn_readlane)
    return __uint_as_float(__builtin_amdgcn_readlane(__float_as_uint(v), l));
#else
    return __shfl(v, l);
#endif
}

__global__ __launch_bounds__(320, 1) void lstm2_kernel(
    const float* __restrict__ x,    // [B, T]
    const float* __restrict__ W1,   // [65, 256]; row0 = x, rows 1..64 = h1
    const float* __restrict__ b1,   // [256]
    const float* __restrict__ W2,   // [65, 4]; rows 0..63 = h1, row 64 = h2
    const float* __restrict__ b2,   // [4]
    float* __restrict__ y)          // [B, T]
{
    __shared__ __align__(16) float xs[TT];
    __shared__ __align__(16) float h1s[2][64];    // parity-buffered h1 (for wave 4)
    __shared__ __align__(16) float gs[2][4][64];  // parity-buffered gates [gate][unit]

    const int tid  = threadIdx.x;
    const int b    = blockIdx.x;
    const int lane = tid & 63;
    const int cw   = tid >> 6;        // 0..3 compute (gate = cw), 4 = layer-2

    // stage x row into LDS (coalesced float4)
    if (tid < 256) {
        ((float4*)xs)[tid] = ((const float4*)(x + (size_t)b * TT))[tid];
    }

    float* yrow = y + (size_t)b * TT;

    if (cw < 4) {
        // ---------------- compute waves ----------------
        const int col = (cw << 6) | lane;     // gate column: gate*64 + unit

        // full column of W1 in registers: 65 weights + bias
        float w[65];
        float bias = b1[col];
        w[0] = W1[col];                       // x-row weight
#pragma unroll
        for (int j = 1; j <= 64; ++j) w[j] = W1[j * 256 + col];   // h1 rows

        // unified activation constants (wave-uniform, branch-free):
        //   act = aa + bb * rcp(1 + exp2(mm*p + kk))
        //   i,o: sigmoid(p); f: sigmoid(p+1); j: tanh(p)
        const float L2E = 1.4426950408889634f;
        const float mm = (cw == 1) ? 2.f * L2E : -L2E;
        const float kk = (cw == 2) ? -L2E : 0.f;
        const float aa = (cw == 1) ? 1.f : 0.f;
        const float bb = (cw == 1) ? -2.f : 1.f;

        float c1 = 0.f;   // cell state of unit `lane` (replicated per wave)
        float hv = 0.f;   // h1[lane] (replicated per wave, REGISTER-resident)
        __syncthreads();  // barrier #1 (xs staged)

        // Anti-remat keep-alive: "+v" makes each w[] an input AND output of
        // the (empty) asm, so the loop-carried value cannot be recomputed
        // from memory -- the allocator must keep it in a VGPR.
#define PIN8(A) asm volatile("" : "+v"(w[A]), "+v"(w[(A)+1]), "+v"(w[(A)+2]), \
        "+v"(w[(A)+3]), "+v"(w[(A)+4]), "+v"(w[(A)+5]), "+v"(w[(A)+6]), "+v"(w[(A)+7]))

        // One step; PAR compile-time. Matvec broadcasts hv lane-by-lane via
        // readlane (pure VALU). Only cross-wave traffic: gs write/read.
#define STEP(PAR, XT) { \
        float a0 = fmaf((XT), w[0], bias), a1 = 0.f, a2 = 0.f, a3 = 0.f; \
        _Pragma("unroll") \
        for (int j = 0; j < 64; j += 4) { \
            a0 = fmaf(bcast(hv, j + 0), w[j + 1], a0); \
            a1 = fmaf(bcast(hv, j + 1), w[j + 2], a1); \
            a2 = fmaf(bcast(hv, j + 2), w[j + 3], a2); \
            a3 = fmaf(bcast(hv, j + 3), w[j + 4], a3); \
        } \
        float p = (a0 + a1) + (a2 + a3); \
        float act = fmaf(bb, __builtin_amdgcn_rcpf(1.f + exp2f(fmaf(mm, p, kk))), aa); \
        gs[PAR][cw][lane] = act; \
        __syncthreads(); \
        { \
            float i_ = gs[PAR][0][lane], j_ = gs[PAR][1][lane]; \
            float f_ = gs[PAR][2][lane], o_ = gs[PAR][3][lane]; \
            c1 = fmaf(c1, f_, i_ * j_); \
            float rr = __builtin_amdgcn_rcpf(1.f + exp2f(c1 * (2.f * 1.4426950408889634f))); \
            hv = fmaf(-2.f, rr * o_, o_); \
            if (cw == 0) h1s[PAR][lane] = hv; \
        } }

        for (int t = 0; t < TT; t += 4) {
            PIN8(0); PIN8(8); PIN8(16); PIN8(24);
            PIN8(32); PIN8(40); PIN8(48); PIN8(56);
            asm volatile("" : "+v"(w[64]), "+v"(bias));
            float4 x4 = *(const float4*)(xs + t);
            STEP(0, x4.x)
            STEP(1, x4.y)
            STEP(0, x4.z)
            STEP(1, x4.w)
        }
#undef STEP
#undef PIN8
        __syncthreads();              // tail barrier (publish h1(TT-1))
    } else {
        // ---------------- wave 4: full layer 2, one step behind ----------------
        float4 w2g4 = *(const float4*)(W2 + lane * 4);   // W2[lane][0..3]
        const float w2h0 = W2[256], w2h1 = W2[257], w2h2 = W2[258], w2h3 = W2[259];
        const float b20 = b2[0], b21 = b2[1], b22 = b2[2], b23 = b2[3];
        float c2 = 0.f, h2 = 0.f;     // state lives in lane 63
        __syncthreads();              // barrier #1

        for (int t = 0; t < TT; ++t) {
            __syncthreads();          // rendezvous with compute mid-step barrier
            if (t > 0) {
                const float hv = h1s[(t - 1) & 1][lane];   // h1(t-1)
                const float d0 = wave_sum64(hv * w2g4.x);
                const float d1 = wave_sum64(hv * w2g4.y);
                const float d2 = wave_sum64(hv * w2g4.z);
                const float d3 = wave_sum64(hv * w2g4.w);
                if (lane == 63) {
                    const float i2 = fsig (fmaf(h2, w2h0, d0) + b20);
                    const float j2 = ftanh(fmaf(h2, w2h1, d1) + b21);
                    const float f2 = fsig (fmaf(h2, w2h2, d2) + b22 + 1.f);
                    const float o2 = fsig (fmaf(h2, w2h3, d3) + b23);
                    c2 = fmaf(c2, f2, i2 * j2);
                    h2 = ftanh(c2) * o2;
                    yrow[t - 1] = h2;
                }
            }
        }
        __syncthreads();              // matches compute tail barrier
        {   // final step (t = TT-1)
            const float hv = h1s[(TT - 1) & 1][lane];
            const float d0 = wave_sum64(hv * w2g4.x);
            const float d1 = wave_sum64(hv * w2g4.y);
            const float d2 = wave_sum64(hv * w2g4.z);
            const float d3 = wave_sum64(hv * w2g4.w);
            if (lane == 63) {
                const float i2 = fsig (fmaf(h2, w2h0, d0) + b20);
                const float j2 = ftanh(fmaf(h2, w2h1, d1) + b21);
                const float f2 = fsig (fmaf(h2, w2h2, d2) + b22 + 1.f);
                const float o2 = fsig (fmaf(h2, w2h3, d3) + b23);
                c2 = fmaf(c2, f2, i2 * j2);
                h2 = ftanh(c2) * o2;
                yrow[TT - 1] = h2;
            }
        }
    }
}

extern "C" void kernel_launch(void* const* d_in, const int* in_sizes, int n_in,
                              void* d_out, int out_size, void* d_ws, size_t ws_size,
                              hipStream_t stream) {
    const float* x  = (const float*)d_in[0];
    const float* W1 = (const float*)d_in[1];
    const float* b1 = (const float*)d_in[2];
    const float* W2 = (const float*)d_in[3];
    const float* b2 = (const float*)d_in[4];
    float* y = (float*)d_out;
    lstm2_kernel<<<512, 320, 0, stream>>>(x, W1, b1, W2, b2, y);
}